// Round 13
// baseline (127.174 us; speedup 1.0000x reference)
//
#include <hip/hip_runtime.h>
#include <hip/hip_bf16.h>
#include <math.h>

typedef __attribute__((ext_vector_type(8))) short bf16x8;
typedef __attribute__((ext_vector_type(4))) float f32x4;

#define NSC    8
#define SLEN   4096
#define FEAT   64
#define NQ     264               // q = 2*c_old + tw; max accessed 261
#define ATAB_B (NQ * 8 * 1024)

// L = int(64 * 64^(i/7)) from np.logspace(0, log10(64), 8)
constexpr int L_[NSC]    = {64, 115, 210, 380, 689, 1248, 2261, 4096};
constexpr int CACT_[NSC] = {3, 5, 8, 13, 23, 40, 72, 129};  // last active c_old

struct WavP { float step[NSC]; float isq[NSC]; };

// ---------------- kernel 1: build MFMA-fragment-ordered A table -----------------
// Atab[q][s][l][j] = w~_s[16q - 32 + (l&15) - 8*(l>>4) - j], zero outside [0,L_s).
__global__ void k_build_atab(const float* __restrict__ mw, const float* __restrict__ sw,
                             __hip_bfloat16* __restrict__ at, WavP wp)
{
  int e = blockIdx.x * 256 + threadIdx.x;       // e < NQ*4096
  int j = e & 7, l = (e >> 3) & 63, s = (e >> 9) & 7, q = e >> 12;
  int k = 16 * q - 32 + (l & 15) - 8 * (l >> 4) - j;
  float val = 0.f;
  if (k >= 0 && k < L_[s]) {
    float pos = (float)k * wp.step[s];
    int ii = (int)pos;
    float r;
    if (ii >= 63) r = mw[s * 64 + 63];
    else {
      float a = mw[s * 64 + ii];
      r = fmaf(pos - (float)ii, mw[s * 64 + ii + 1] - a, a);
    }
    val = r * wp.isq[s] * sw[s];
  }
  at[e] = __float2bfloat16(val);
}

// ---------------- kernel 2: signal f32 [b][r][f] -> bf16 FRAGMENT-ORDERED -------
// Per 64-row chunk (b*64+rb): element e = h*2048 + n*512 + l*8 + i holds
// sig[r = rb*64 + h*32 + (l>>4)*8 + i][f = n*16 + (l&15)].  Vectorized both ways.
__global__ __launch_bounds__(256) void k_transpose(const float* __restrict__ sig,
                                                   __hip_bfloat16* __restrict__ sigT2)
{
  __shared__ float t[4096];                 // flat [r][f], XOR-swizzled banks
  const int tid = threadIdx.x;
  const float* sp = sig + (size_t)blockIdx.x * 4096;
  #pragma unroll
  for (int q2 = 0; q2 < 4; ++q2) {          // 1024 float4s -> all 4096 elems
    int i4 = tid + 256 * q2;
    float4 v = ((const float4*)sp)[i4];     // 4 consecutive f, same row
    int r = i4 >> 4, f0 = (i4 & 15) << 2;
    #pragma unroll
    for (int u = 0; u < 4; ++u)
      t[(r << 6) + ((f0 + u) ^ ((r & 7) << 3))] = ((const float*)&v)[u];
  }
  __syncthreads();
  __hip_bfloat16* op = sigT2 + (size_t)blockIdx.x * 4096;
  #pragma unroll
  for (int w = 0; w < 2; ++w) {
    const int e0 = tid * 16 + w * 8;        // 8 consecutive e: same h,n,l; i=u
    const int h = e0 >> 11, n = (e0 >> 9) & 3, ll = (e0 >> 3) & 63;
    const int f = n * 16 + (ll & 15);
    const int rb = h * 32 + ((ll >> 4) << 3);
    bf16x8 o;
    #pragma unroll
    for (int u = 0; u < 8; ++u) {
      int r = rb + u;
      __hip_bfloat16 hb = __float2bfloat16(t[(r << 6) + (f ^ ((r & 7) << 3))]);
      o[u] = *reinterpret_cast<short*>(&hb);
    }
    *(bf16x8*)(op + e0) = o;
  }
}

// ---------------- kernel 3 helpers (R9 known-good structure) --------------------
template<int SB>
__device__ __forceinline__ void loadA4(const char* aw, int c_old, bf16x8* A) {
  #pragma unroll
  for (int i = 0; i < 4; ++i)
    if (c_old <= CACT_[SB + i])
      A[i] = *(const bf16x8*)(aw + (size_t)c_old * 16384 + (SB + i) * 1024);
}

template<int SB>
__device__ __forceinline__ void stepMFMA(int c_old, const bf16x8* A, const bf16x8* B,
                                         f32x4 (*acc)[4]) {
  __builtin_amdgcn_s_setprio(1);
  #pragma unroll
  for (int i = 3; i >= 0; --i) {
    if (c_old <= CACT_[SB + i]) {          // wave-uniform; static indices
      acc[i][0] = __builtin_amdgcn_mfma_f32_16x16x32_bf16(A[i], B[0], acc[i][0], 0, 0, 0);
      acc[i][1] = __builtin_amdgcn_mfma_f32_16x16x32_bf16(A[i], B[1], acc[i][1], 0, 0, 0);
      acc[i][2] = __builtin_amdgcn_mfma_f32_16x16x32_bf16(A[i], B[2], acc[i][2], 0, 0, 0);
      acc[i][3] = __builtin_amdgcn_mfma_f32_16x16x32_bf16(A[i], B[3], acc[i][3], 0, 0, 0);
    }
  }
  __builtin_amdgcn_s_setprio(0);
}

// One 4-scale pass over one tile. B staged per block into LDS (16KB super-chunk
// = 4 k-steps, double-buffered via global_load_lds); A global 2-step-ahead.
template<int SB>
__device__ __forceinline__ void run_pass(const char* aw, const char* sgb,
                                         short (*lbuf)[8192], int nsteps,
                                         int tid, int l, float* ob, int trow, int fl)
{
  f32x4 acc[4][4];
  const f32x4 z = {0.f, 0.f, 0.f, 0.f};
  #pragma unroll
  for (int i = 0; i < 4; ++i)
    #pragma unroll
    for (int n = 0; n < 4; ++n) acc[i][n] = z;

  const int nsc = (nsteps + 3) >> 2;

  auto stage = [&](int sc) {   // stages steps 4sc..4sc+3 (chunks 2sc+1, 2sc)
    const char* gp = sgb - (size_t)(2 * sc + 1) * 8192 + tid * 16;
    char* lp = (char*)lbuf[sc & 1] + (tid >> 6) * 1024;
    #pragma unroll
    for (int it = 0; it < 4; ++it)
      __builtin_amdgcn_global_load_lds(
        (const __attribute__((address_space(1))) void*)(gp + it * 4096),
        (__attribute__((address_space(3))) void*)(lp + it * 4096), 16, 0, 0);
  };
  auto ldB = [&](int sc, int st, bf16x8* B) {
    const char* p = (const char*)lbuf[sc & 1] + (3 - (st & 3)) * 4096 + l * 16;
    #pragma unroll
    for (int n = 0; n < 4; ++n)
      B[n] = *(const bf16x8*)(p + n * 1024);
  };

  bf16x8 A0[4], A1[4], B0[4], B1[4];
  stage(0);
  loadA4<SB>(aw, 0, A0);
  loadA4<SB>(aw, 1, A1);
  __syncthreads();                        // stage(0) drained + all waves synced

  for (int sc = 0; sc < nsc; ++sc) {
    const int st = 4 * sc;
    if (sc + 1 < nsc) stage(sc + 1);      // overlaps this body's compute
    ldB(sc, st, B0);
    if (st + 1 < nsteps) ldB(sc, st + 1, B1);
    stepMFMA<SB>(st, A0, B0, acc);
    loadA4<SB>(aw, st + 2, A0);
    if (st + 2 < nsteps) ldB(sc, st + 2, B0);
    if (st + 1 < nsteps) stepMFMA<SB>(st + 1, A1, B1, acc);
    loadA4<SB>(aw, st + 3, A1);
    if (st + 3 < nsteps) ldB(sc, st + 3, B1);
    if (st + 2 < nsteps) stepMFMA<SB>(st + 2, A0, B0, acc);
    loadA4<SB>(aw, st + 4, A0);           // next body's first steps
    if (st + 3 < nsteps) stepMFMA<SB>(st + 3, A1, B1, acc);
    loadA4<SB>(aw, st + 5, A1);
    __syncthreads();                      // drains stage(sc+1) + syncs waves
  }

  #pragma unroll
  for (int i = 0; i < 4; ++i) {
    float* os = ob + (size_t)(SB + i) * SLEN * FEAT;
    #pragma unroll
    for (int n = 0; n < 4; ++n)
      #pragma unroll
      for (int r = 0; r < 4; ++r)
        os[(size_t)(trow + r) * FEAT + n * 16 + fl] = acc[i][n][r];
  }
}

// ---------------- kernel 3: banded-Toeplitz MFMA convolution --------------------
// PERFECT STATIC BALANCE: block (x, y): x = pair*16 + batch handles tiles
// {63-pair, pair} sequentially; y selects scale group (0: scales 4-7 heavy,
// 1: scales 0-3 light, k-truncated). Heavy blocks = exactly 65 chunk-units each;
// with x-major striping every CU gets {2 heavy + 2 light} = uniform work.
__global__ __launch_bounds__(256, 3) void k_wavelet_mfma(
    const __hip_bfloat16* __restrict__ sigT2,
    const __hip_bfloat16* __restrict__ atab,
    float* __restrict__ out)
{
  __shared__ __align__(16) short lbuf[2][8192];   // 2 x 16KB B super-chunks

  const int tid  = threadIdx.x;
  const int p    = blockIdx.x >> 4;       // tile pair id, 0..31
  const int b    = blockIdx.x & 15;       // batch
  const int pass = blockIdx.y;            // 0: scales 4-7, 1: scales 0-3
  const int tw   = tid >> 6;              // wave id
  const int l    = tid & 63;              // lane
  const int fl   = tid & 15;              // lane&15: A-row / B-col / D-col
  const int g    = (tid >> 4) & 3;        // lane>>4: k-group / D-row-group

  const char* aw = (const char*)atab + tw * 8192 + (size_t)l * 16;
  float* ob = out + (size_t)b * NSC * SLEN * FEAT;

  #pragma unroll
  for (int which = 0; which < 2; ++which) {
    const int tt = which ? p : 63 - p;    // heavy tile first
    const int C  = tt + 1;
    const char* sgb = (const char*)sigT2 + (size_t)(b * 64 + tt) * 8192;
    const int trow  = tt * 64 + tw * 16 + g * 4;   // D row=4g+reg, col=16n+fl
    if (pass == 0)
      run_pass<4>(aw, sgb, lbuf, 2 * C, tid, l, ob, trow, fl);
    else
      run_pass<0>(aw, sgb, lbuf, min(2 * C, 14), tid, l, ob, trow, fl);
  }
}

extern "C" void kernel_launch(void* const* d_in, const int* in_sizes, int n_in,
                              void* d_out, int out_size, void* d_ws, size_t ws_size,
                              hipStream_t stream) {
  const float* sig = (const float*)d_in[0];
  const float* mw  = (const float*)d_in[1];
  const float* sw  = (const float*)d_in[2];
  float*       out = (float*)d_out;

  // workspace: [0, ATAB_B) A-fragment table; sigT2 at 0x240000 (guard gap below
  // sigT2 absorbs the 8KB negative dangle of stage(0) at tt=0, b=0)
  __hip_bfloat16* atab  = (__hip_bfloat16*)d_ws;
  __hip_bfloat16* sigT2 = (__hip_bfloat16*)((char*)d_ws + 0x240000);

  WavP wp;
  const double lg = log10(64.0), st = lg / 7.0;
  for (int i = 0; i < NSC; ++i) {
    double y = (i == 7) ? lg : (double)i * st;
    double s = pow(10.0, y);
    wp.step[i] = (float)(63.0 / (double)(L_[i] - 1));
    wp.isq[i]  = (float)(1.0 / sqrt(s));
  }

  k_build_atab<<<NQ * 16, 256, 0, stream>>>(mw, sw, atab, wp);
  k_transpose<<<1024, 256, 0, stream>>>(sig, sigT2);
  k_wavelet_mfma<<<dim3(512, 2), 256, 0, stream>>>(sigT2, atab, out);
}